// Round 6
// baseline (3626.600 us; speedup 1.0000x reference)
//
#include <hip/hip_runtime.h>

typedef unsigned short u16;
typedef __attribute__((ext_vector_type(8))) short s8v;

#define L_DIM 1024
#define N_DIM 16384
#define R_DIM 128
#define PEN  -10000.0f

__device__ __forceinline__ float b2f(u16 x) { return __uint_as_float(((unsigned)x) << 16); }
__device__ __forceinline__ u16 f2bf(float f) {
    unsigned u = __float_as_uint(f);
    unsigned r = (u + 0x7FFFu + ((u >> 16) & 1u)) >> 16;
    return (u16)r;
}
__device__ __forceinline__ unsigned fmapu(float f) {
    unsigned u = __float_as_uint(f);
    return (u & 0x80000000u) ? ~u : (u | 0x80000000u);
}
__device__ __forceinline__ float funmap(unsigned u) {
    unsigned b = (u & 0x80000000u) ? (u & 0x7fffffffu) : ~u;
    return __uint_as_float(b);
}
// flag=0: 4-byte elements (int32 OR float32 bools); flag=1: 1-byte elements
__device__ __forceinline__ int mask_ok(const void* al, int fl, size_t idx) {
    if (fl) return ((const unsigned char*)al)[idx] != 0;
    return ((const unsigned*)al)[idx] != 0u;
}
// log of bf16-linear E entry, sentinel for exact zero
__device__ __forceinline__ float loge(u16 x) {
    float e = b2f(x);
    return (e > 0.f) ? __logf(e) : -1.0e30f;
}

__device__ __forceinline__ float blk_max(float x, float* scr) {
#pragma unroll
    for (int o = 32; o > 0; o >>= 1) x = fmaxf(x, __shfl_xor(x, o));
    __syncthreads();
    if ((threadIdx.x & 63) == 0) scr[threadIdx.x >> 6] = x;
    __syncthreads();
    return fmaxf(fmaxf(scr[0], scr[1]), fmaxf(scr[2], scr[3]));
}
__device__ __forceinline__ float blk_sum(float x, float* scr) {
#pragma unroll
    for (int o = 32; o > 0; o >>= 1) x += __shfl_xor(x, o);
    __syncthreads();
    if ((threadIdx.x & 63) == 0) scr[threadIdx.x >> 6] = x;
    __syncthreads();
    return scr[0] + scr[1] + scr[2] + scr[3];
}

// -------- detect allowed element width --------------------------------------
__global__ void detect_k(const unsigned* __restrict__ a, int* __restrict__ flag) {
    int bad = 0;
    for (int i = threadIdx.x; i < 4096; i += 256) {
        unsigned w = a[i];
        if (w != 0u && w != 1u && w != 0x3F800000u) bad = 1;
    }
    if (bad) *flag = 1;
}

// -------- per-row top-128 (radix select) + log_softmax over the set ---------
__global__ __launch_bounds__(256) void topk_lsm_k(const float* __restrict__ U,
                                                  int* __restrict__ candg,
                                                  float* __restrict__ lsmg) {
    const int t = blockIdx.x;
    const float* row = U + (size_t)t * N_DIM;
    __shared__ unsigned hist[256];
    __shared__ int sel[2];
    __shared__ int cnts[2];
    __shared__ float vals[128];
    __shared__ int inds[128];
    __shared__ float scr[4];
    const int tid = threadIdx.x;
    unsigned prefix = 0;
    int kneed = 128;
    for (int pass = 0; pass < 4; ++pass) {
        const int sh = 24 - pass * 8;
        hist[tid] = 0;
        __syncthreads();
        for (int i = tid; i < N_DIM; i += 256) {
            unsigned u = __float_as_uint(row[i]);
            unsigned k = (u & 0x80000000u) ? ~u : (u | 0x80000000u);
            bool match = (pass == 0) || ((k >> (sh + 8)) == prefix);
            if (match) atomicAdd(&hist[(k >> sh) & 255u], 1u);
        }
        __syncthreads();
        if (tid == 0) {
            int acc = 0, d = 0;
            for (int dig = 255; dig >= 0; --dig) {
                int c = (int)hist[dig];
                if (acc + c >= kneed) { d = dig; break; }
                acc += c;
            }
            sel[0] = d; sel[1] = acc;
        }
        __syncthreads();
        kneed -= sel[1];
        prefix = (prefix << 8) | (unsigned)sel[0];
        __syncthreads();
    }
    const unsigned K = prefix;
    if (tid < 2) cnts[tid] = 0;
    if (tid < 128) { vals[tid] = -1.0e30f; inds[tid] = 0; }
    __syncthreads();
    for (int i = tid; i < N_DIM; i += 256) {
        float f = row[i];
        unsigned u = __float_as_uint(f);
        unsigned k = (u & 0x80000000u) ? ~u : (u | 0x80000000u);
        if (k > K) { int p = atomicAdd(&cnts[0], 1); if (p < 128) { vals[p] = f; inds[p] = i; } }
    }
    __syncthreads();
    const int cgt = min(cnts[0], 128);
    for (int i = tid; i < N_DIM; i += 256) {
        float f = row[i];
        unsigned u = __float_as_uint(f);
        unsigned k = (u & 0x80000000u) ? ~u : (u | 0x80000000u);
        if (k == K) {
            int p = atomicAdd(&cnts[1], 1);
            if (cgt + p < 128) { vals[cgt + p] = f; inds[cgt + p] = i; }
        }
    }
    __syncthreads();
    float xv = (tid < 128) ? vals[tid] : -3.0e38f;
    float mx = blk_max(xv, scr);
    float ex = (tid < 128) ? __expf(vals[tid] - mx) : 0.f;
    float sm = blk_sum(ex, scr);
    float lse = mx + __logf(fmaxf(sm, 1e-37f));
    if (tid < 128) {
        candg[t * 128 + tid] = min(max(inds[tid], 0), N_DIM - 1);
        lsmg[t * 128 + tid] = vals[tid] - lse;
    }
}

// -------- cast H to bf16 ----------------------------------------------------
__global__ void cast_h_k(const float* __restrict__ H, u16* __restrict__ Hbf) {
    size_t base = ((size_t)blockIdx.x * 256 + threadIdx.x) * 4;
    float4 f = *(const float4*)(H + base);
    ushort4 o;
    o.x = f2bf(f.x); o.y = f2bf(f.y); o.z = f2bf(f.z); o.w = f2bf(f.w);
    *(ushort4*)(Hbf + base) = o;
}

// -------- HW = H @ W (fp32 VALU, bf16 out); 8 rows per block ----------------
__global__ __launch_bounds__(256) void gemm_hw_k(const float* __restrict__ H,
                                                 const float* __restrict__ W,
                                                 u16* __restrict__ HWbf) {
    const int r0 = blockIdx.x * 8;
    __shared__ float Hl[8][512];
    for (int idx = threadIdx.x; idx < 8 * 512; idx += 256) {
        int r = idx >> 9, k = idx & 511;
        Hl[r][k] = H[(size_t)(r0 + r) * 512 + k];
    }
    __syncthreads();
    const int c = threadIdx.x;
    float acc0[8], acc1[8];
#pragma unroll
    for (int r = 0; r < 8; ++r) { acc0[r] = 0.f; acc1[r] = 0.f; }
    for (int k = 0; k < 512; ++k) {
        float w0 = W[(size_t)k * 512 + c];
        float w1 = W[(size_t)k * 512 + c + 256];
#pragma unroll
        for (int r = 0; r < 8; ++r) {
            float h = Hl[r][k];
            acc0[r] += h * w0;
            acc1[r] += h * w1;
        }
    }
#pragma unroll
    for (int r = 0; r < 8; ++r) {
        HWbf[(size_t)(r0 + r) * 512 + c] = f2bf(acc0[r]);
        HWbf[(size_t)(r0 + r) * 512 + c + 256] = f2bf(acc1[r]);
    }
}

// -------- per-step pair matrix -> (E row-major bf16, c fp32), pure VALU -----
__global__ __launch_bounds__(256) void pair_k(const int* __restrict__ candg,
                                              const float* __restrict__ lsmg,
                                              const u16* __restrict__ HWbf,
                                              const u16* __restrict__ Hbf,
                                              const void* __restrict__ allowed,
                                              const int* __restrict__ flag,
                                              u16* __restrict__ Eg,
                                              float* __restrict__ cvec) {
    const int t = blockIdx.x + 1;
    __shared__ u16 Hl[32][520];
    __shared__ int sprev[128], scur[128];
    __shared__ unsigned scm[32];
    __shared__ float scmf[32];
    const int tid = threadIdx.x;
    if (tid < 128) {
        sprev[tid] = min(max(candg[(t - 1) * 128 + tid], 0), N_DIM - 1);
        scur[tid]  = min(max(candg[t * 128 + tid], 0), N_DIM - 1);
    }
    __syncthreads();
    const int fl = *flag;
    const int i = tid >> 1;               // prev row 0..127
    const int jh = tid & 1;               // 16-column half of a 32-col pass
    const size_t prow = (size_t)sprev[i] * 512;
    u16* Eo = Eg + (size_t)(t - 1) * 16384;
    for (int p = 0; p < 4; ++p) {
        for (int idx = tid; idx < 32 * 64; idx += 256) {
            int r = idx >> 6, v = idx & 63;
            *(s8v*)&Hl[r][v * 8] = *(const s8v*)(Hbf + (size_t)scur[p * 32 + r] * 512 + v * 8);
        }
        if (tid < 32) scm[tid] = 0u;
        __syncthreads();
        float acc[16];
#pragma unroll
        for (int jj = 0; jj < 16; ++jj) acc[jj] = 0.f;
        for (int k8 = 0; k8 < 64; ++k8) {
            s8v hv = *(const s8v*)(HWbf + prow + k8 * 8);
            float a[8];
#pragma unroll
            for (int e = 0; e < 8; ++e) a[e] = b2f((u16)hv[e]);
#pragma unroll
            for (int jj = 0; jj < 16; ++jj) {
                s8v hl = *(const s8v*)&Hl[jh * 16 + jj][k8 * 8];
#pragma unroll
                for (int e = 0; e < 8; ++e) acc[jj] += a[e] * b2f((u16)hl[e]);
            }
        }
#pragma unroll
        for (int jj = 0; jj < 16; ++jj) {
            int jl = jh * 16 + jj;
            int j = p * 32 + jl;
            if (!mask_ok(allowed, fl, (size_t)scur[j] * N_DIM + (size_t)sprev[i])) acc[jj] += PEN;
            atomicMax(&scm[jl], fmapu(acc[jj]));
        }
        __syncthreads();
        if (tid < 32) {
            float cm = funmap(scm[tid]);
            scmf[tid] = cm;
            cvec[(size_t)(t - 1) * 128 + p * 32 + tid] = cm + lsmg[(size_t)t * 128 + p * 32 + tid];
        }
        __syncthreads();
#pragma unroll
        for (int jj = 0; jj < 16; ++jj) {
            int jl = jh * 16 + jj;
            float e = __expf(acc[jj] - scmf[jl]);      // arg <= 0 by construction
            e = fminf(fmaxf(e, 0.f), 1.0f);            // scrub any NaN/overshoot
            Eo[(size_t)i * 128 + p * 32 + jl] = f2bf(e);
        }
        __syncthreads();
    }
}

// -------- gold path scores --------------------------------------------------
__global__ __launch_bounds__(256) void score_k(const float* __restrict__ U,
                                               const int* __restrict__ gold,
                                               const void* __restrict__ allowed,
                                               const int* __restrict__ flag,
                                               const u16* __restrict__ HWbf,
                                               const u16* __restrict__ Hbf,
                                               float* __restrict__ accums) {
    const int t = blockIdx.x;
    __shared__ float scr[4];
    float part = 0.f;
    int gp = 0, gc = 0;
    if (t < L_DIM - 1) {
        gp = min(max(gold[t], 0), N_DIM - 1);
        gc = min(max(gold[t + 1], 0), N_DIM - 1);
        const u16* ar = HWbf + (size_t)gp * 512;
        const u16* br = Hbf + (size_t)gc * 512;
        for (int k = threadIdx.x; k < 512; k += 256)
            part += b2f(ar[k]) * b2f(br[k]);
    }
    float tot = blk_sum(part, scr);
    if (threadIdx.x == 0) {
        if (t < L_DIM - 1) {
            int ok = mask_ok(allowed, *flag, (size_t)gc * N_DIM + (size_t)gp);
            atomicAdd(&accums[1], ok ? tot : PEN);
        }
        int g0 = min(max(gold[t], 0), N_DIM - 1);
        atomicAdd(&accums[0], U[(size_t)t * N_DIM + g0]);
    }
}

// ===================== log-domain fp32 binary tree ==========================
// Matrices M[i][k] in log domain, fp32. Combine: C = A o B,
// C[i][k] = max_j(A[i][j]+B[j][k]) + log(sum_j exp(A[i][j]+B[j][k]-max)).
// Per-entry max-subtraction => unbounded dynamic range (the r4 failure mode
// cannot occur). Sentinels stay finite: worst -1e30 * 2^levels << fp32 max.
// Row-split: blockIdx.y in {0,1} handles 64 output rows.

// Level 1: inputs are pair_k's (E bf16 [i][k], c fp32 [k]); P[i][k]=log(E)+c[k]
__global__ __launch_bounds__(256) void l1comb_k(const u16* __restrict__ Eg,
                                                const float* __restrict__ cvec,
                                                float* __restrict__ Mout,
                                                int n_in) {
    const int o = blockIdx.x, rs = blockIdx.y;
    const int tid = threadIdx.x;
    const u16* E0 = Eg + (size_t)(2 * o) * 16384;
    const float* c0 = cvec + (size_t)(2 * o) * 128;
    float* C = Mout + (size_t)o * 16384;
    if (2 * o + 1 >= n_in) {   // pass-through convert
        for (int idx = tid; idx < 64 * 128; idx += 256) {
            int i = rs * 64 + (idx >> 7), k = idx & 127;
            C[(size_t)i * 128 + k] = loge(E0[(size_t)i * 128 + k]) + c0[k];
        }
        return;
    }
    __shared__ float At[128][64];     // A^T: At[j][i_local] = log E0[i][j] + c0[j]
    __shared__ float Bs[128 * 128];   // B:  Bs[j*128+k]    = log E1[j][k] + c1[k]
    __shared__ float sc0[128], sc1[128];
    const u16* E1 = Eg + (size_t)(2 * o + 1) * 16384;
    const float* c1 = cvec + (size_t)(2 * o + 1) * 128;
    if (tid < 128) { sc0[tid] = c0[tid]; sc1[tid] = c1[tid]; }
    __syncthreads();
    for (int idx = tid; idx < 64 * 128; idx += 256) {
        int il = idx & 63, j = idx >> 6;
        At[j][il] = loge(E0[(size_t)(rs * 64 + il) * 128 + j]) + sc0[j];
    }
    for (int idx = tid; idx < 16384; idx += 256)
        Bs[idx] = loge(E1[idx]) + sc1[idx & 127];
    __syncthreads();
    const int i0 = (tid & 15) * 4, k0 = (tid >> 4) * 8;
    float m[4][8], s[4][8];
#pragma unroll
    for (int a = 0; a < 4; ++a)
#pragma unroll
        for (int b = 0; b < 8; ++b) m[a][b] = -3.0e38f;
    for (int j = 0; j < 128; ++j) {
        float4 av = *(const float4*)&At[j][i0];
        float4 b0 = *(const float4*)&Bs[j * 128 + k0];
        float4 b1 = *(const float4*)&Bs[j * 128 + k0 + 4];
        float aa[4] = {av.x, av.y, av.z, av.w};
        float bb[8] = {b0.x, b0.y, b0.z, b0.w, b1.x, b1.y, b1.z, b1.w};
#pragma unroll
        for (int a = 0; a < 4; ++a)
#pragma unroll
            for (int b = 0; b < 8; ++b) m[a][b] = fmaxf(m[a][b], aa[a] + bb[b]);
    }
#pragma unroll
    for (int a = 0; a < 4; ++a)
#pragma unroll
        for (int b = 0; b < 8; ++b) s[a][b] = 0.f;
    for (int j = 0; j < 128; ++j) {
        float4 av = *(const float4*)&At[j][i0];
        float4 b0 = *(const float4*)&Bs[j * 128 + k0];
        float4 b1 = *(const float4*)&Bs[j * 128 + k0 + 4];
        float aa[4] = {av.x, av.y, av.z, av.w};
        float bb[8] = {b0.x, b0.y, b0.z, b0.w, b1.x, b1.y, b1.z, b1.w};
#pragma unroll
        for (int a = 0; a < 4; ++a)
#pragma unroll
            for (int b = 0; b < 8; ++b) s[a][b] += __expf(aa[a] + bb[b] - m[a][b]);
    }
#pragma unroll
    for (int a = 0; a < 4; ++a)
#pragma unroll
        for (int b = 0; b < 8; ++b)
            C[(size_t)(rs * 64 + i0 + a) * 128 + k0 + b] = m[a][b] + __logf(s[a][b]); // s>=1
}

// Levels 2+: fp32 log matrices in/out
__global__ __launch_bounds__(256) void comb_k(const float* __restrict__ Min,
                                              float* __restrict__ Mout, int n_in) {
    const int o = blockIdx.x, rs = blockIdx.y;
    const int tid = threadIdx.x;
    const float* A = Min + (size_t)(2 * o) * 16384;
    float* C = Mout + (size_t)o * 16384;
    if (2 * o + 1 >= n_in) {
        for (int idx = tid; idx < 64 * 128; idx += 256) {
            int i = rs * 64 + (idx >> 7), k = idx & 127;
            C[(size_t)i * 128 + k] = A[(size_t)i * 128 + k];
        }
        return;
    }
    __shared__ float At[128][64];
    __shared__ float Bs[128 * 128];
    const float* B = Min + (size_t)(2 * o + 1) * 16384;
    for (int idx = tid; idx < 64 * 128; idx += 256) {
        int il = idx & 63, j = idx >> 6;
        At[j][il] = A[(size_t)(rs * 64 + il) * 128 + j];
    }
    for (int idx = tid; idx < 16384; idx += 256) Bs[idx] = B[idx];
    __syncthreads();
    const int i0 = (tid & 15) * 4, k0 = (tid >> 4) * 8;
    float m[4][8], s[4][8];
#pragma unroll
    for (int a = 0; a < 4; ++a)
#pragma unroll
        for (int b = 0; b < 8; ++b) m[a][b] = -3.0e38f;
    for (int j = 0; j < 128; ++j) {
        float4 av = *(const float4*)&At[j][i0];
        float4 b0 = *(const float4*)&Bs[j * 128 + k0];
        float4 b1 = *(const float4*)&Bs[j * 128 + k0 + 4];
        float aa[4] = {av.x, av.y, av.z, av.w};
        float bb[8] = {b0.x, b0.y, b0.z, b0.w, b1.x, b1.y, b1.z, b1.w};
#pragma unroll
        for (int a = 0; a < 4; ++a)
#pragma unroll
            for (int b = 0; b < 8; ++b) m[a][b] = fmaxf(m[a][b], aa[a] + bb[b]);
    }
#pragma unroll
    for (int a = 0; a < 4; ++a)
#pragma unroll
        for (int b = 0; b < 8; ++b) s[a][b] = 0.f;
    for (int j = 0; j < 128; ++j) {
        float4 av = *(const float4*)&At[j][i0];
        float4 b0 = *(const float4*)&Bs[j * 128 + k0];
        float4 b1 = *(const float4*)&Bs[j * 128 + k0 + 4];
        float aa[4] = {av.x, av.y, av.z, av.w};
        float bb[8] = {b0.x, b0.y, b0.z, b0.w, b1.x, b1.y, b1.z, b1.w};
#pragma unroll
        for (int a = 0; a < 4; ++a)
#pragma unroll
            for (int b = 0; b < 8; ++b) s[a][b] += __expf(aa[a] + bb[b] - m[a][b]);
    }
#pragma unroll
    for (int a = 0; a < 4; ++a)
#pragma unroll
        for (int b = 0; b < 8; ++b)
            C[(size_t)(rs * 64 + i0 + a) * 128 + k0 + b] = m[a][b] + __logf(s[a][b]);
}

// -------- final: alpha0 through 32 composed log-matrices, logZ, output ------
__global__ __launch_bounds__(256) void tfinal_k(const float* __restrict__ M5,
                                                const float* __restrict__ lsmg,
                                                const float* __restrict__ accums,
                                                float* __restrict__ out) {
    __shared__ float v[128];
    __shared__ float scr[4];
    const int tid = threadIdx.x;
    if (tid < 128) v[tid] = lsmg[tid];   // alpha0
    __syncthreads();
    for (int s = 0; s < 32; ++s) {
        const float* M = M5 + (size_t)s * 16384;
        float nv = -3.0e38f;
        if (tid < 128) {
            float m = -3.0e38f;
            for (int i = 0; i < 128; ++i) m = fmaxf(m, v[i] + M[(size_t)i * 128 + tid]);
            float sum = 0.f;
            for (int i = 0; i < 128; ++i) sum += __expf(v[i] + M[(size_t)i * 128 + tid] - m);
            nv = m + __logf(sum);   // sum >= 1
        }
        __syncthreads();
        if (tid < 128) v[tid] = nv;
        __syncthreads();
    }
    float x = (tid < 128) ? v[tid] : -3.0e38f;
    float mz = blk_max(x, scr);
    float e = (tid < 128) ? __expf(v[tid] - mz) : 0.f;
    float sm = blk_sum(e, scr);
    if (tid == 0) out[0] = mz + __logf(fmaxf(sm, 1e-37f)) - (accums[0] + accums[1]);
}

extern "C" void kernel_launch(void* const* d_in, const int* in_sizes, int n_in,
                              void* d_out, int out_size, void* d_ws, size_t ws_size,
                              hipStream_t stream) {
    const float* U = (const float*)d_in[0];
    const float* H = (const float*)d_in[1];
    const float* W = (const float*)d_in[2];
    const int* gold = (const int*)d_in[3];
    const void* allowed = (const void*)d_in[4];

    char* ws = (char*)d_ws;
    float* accums = (float*)ws;            // [0]=score_unary, [1]=score_pair
    int* flag = (int*)(ws + 8);
    size_t off = 256;
    int* cand = (int*)(ws + off);     off += (size_t)L_DIM * R_DIM * 4;
    float* lsm = (float*)(ws + off);  off += (size_t)L_DIM * R_DIM * 4;
    u16* Hbf = (u16*)(ws + off);      off += (size_t)N_DIM * 512 * 2;      // 16 MB
    u16* HWbf = (u16*)(ws + off);     off += (size_t)N_DIM * 512 * 2;      // 16 MB
    u16* E = (u16*)(ws + off);        off += (size_t)(L_DIM - 1) * 16384 * 2; // 32 MB
    float* cvec = (float*)(ws + off); off += (size_t)(L_DIM - 1) * 128 * 4;

    // Tree buffers OVERLAY dead regions (ws stays at the r5-verified 66.5 MB):
    // MA (32 MB) = Hbf+HWbf region — dead after score_k, written by L1.
    // MB (16 MB) = E region       — dead after L1 reads it, written by L2.
    float* MA = (float*)Hbf;
    float* MB = (float*)E;

    hipMemsetAsync(d_ws, 0, 256, stream);
    detect_k<<<1, 256, 0, stream>>>((const unsigned*)d_in[4], flag);
    topk_lsm_k<<<L_DIM, 256, 0, stream>>>(U, cand, lsm);
    cast_h_k<<<(N_DIM * 512) / (256 * 4), 256, 0, stream>>>(H, Hbf);
    gemm_hw_k<<<N_DIM / 8, 256, 0, stream>>>(H, W, HWbf);
    pair_k<<<L_DIM - 1, 256, 0, stream>>>(cand, lsm, HWbf, Hbf, allowed, flag, E, cvec);
    score_k<<<L_DIM, 256, 0, stream>>>(U, gold, allowed, flag, HWbf, Hbf, accums);
    // binary tree: 1023 -> 512 -> 256 -> 128 -> 64 -> 32, then 32-step scan
    l1comb_k<<<dim3(512, 2), 256, 0, stream>>>(E, cvec, MA, 1023);
    comb_k<<<dim3(256, 2), 256, 0, stream>>>(MA, MB, 512);
    comb_k<<<dim3(128, 2), 256, 0, stream>>>(MB, MA, 256);
    comb_k<<<dim3(64, 2), 256, 0, stream>>>(MA, MB, 128);
    comb_k<<<dim3(32, 2), 256, 0, stream>>>(MB, MA, 64);
    tfinal_k<<<1, 256, 0, stream>>>(MA, lsm, accums, (float*)d_out);
}

// Round 7
// 3015.632 us; speedup vs baseline: 1.2026x; 1.2026x over previous
//
#include <hip/hip_runtime.h>

typedef unsigned short u16;
typedef __attribute__((ext_vector_type(8))) short s8v;

#define L_DIM 1024
#define N_DIM 16384
#define R_DIM 128
#define PEN  -10000.0f

__device__ __forceinline__ float b2f(u16 x) { return __uint_as_float(((unsigned)x) << 16); }
__device__ __forceinline__ u16 f2bf(float f) {
    unsigned u = __float_as_uint(f);
    unsigned r = (u + 0x7FFFu + ((u >> 16) & 1u)) >> 16;
    return (u16)r;
}
__device__ __forceinline__ unsigned fmapu(float f) {
    unsigned u = __float_as_uint(f);
    return (u & 0x80000000u) ? ~u : (u | 0x80000000u);
}
__device__ __forceinline__ float funmap(unsigned u) {
    unsigned b = (u & 0x80000000u) ? (u & 0x7fffffffu) : ~u;
    return __uint_as_float(b);
}
// flag=0: 4-byte elements (int32 OR float32 bools); flag=1: 1-byte elements
__device__ __forceinline__ int mask_ok(const void* al, int fl, size_t idx) {
    if (fl) return ((const unsigned char*)al)[idx] != 0;
    return ((const unsigned*)al)[idx] != 0u;
}
// log of bf16-linear E entry, sentinel for exact zero
__device__ __forceinline__ float loge(u16 x) {
    float e = b2f(x);
    return (e > 0.f) ? __logf(e) : -1.0e30f;
}

__device__ __forceinline__ float blk_max(float x, float* scr) {
#pragma unroll
    for (int o = 32; o > 0; o >>= 1) x = fmaxf(x, __shfl_xor(x, o));
    __syncthreads();
    if ((threadIdx.x & 63) == 0) scr[threadIdx.x >> 6] = x;
    __syncthreads();
    return fmaxf(fmaxf(scr[0], scr[1]), fmaxf(scr[2], scr[3]));
}
__device__ __forceinline__ float blk_sum(float x, float* scr) {
#pragma unroll
    for (int o = 32; o > 0; o >>= 1) x += __shfl_xor(x, o);
    __syncthreads();
    if ((threadIdx.x & 63) == 0) scr[threadIdx.x >> 6] = x;
    __syncthreads();
    return scr[0] + scr[1] + scr[2] + scr[3];
}

// -------- detect allowed element width --------------------------------------
__global__ void detect_k(const unsigned* __restrict__ a, int* __restrict__ flag) {
    int bad = 0;
    for (int i = threadIdx.x; i < 4096; i += 256) {
        unsigned w = a[i];
        if (w != 0u && w != 1u && w != 0x3F800000u) bad = 1;
    }
    if (bad) *flag = 1;
}

// -------- per-row top-128 (radix select) + log_softmax over the set ---------
__global__ __launch_bounds__(256) void topk_lsm_k(const float* __restrict__ U,
                                                  int* __restrict__ candg,
                                                  float* __restrict__ lsmg) {
    const int t = blockIdx.x;
    const float* row = U + (size_t)t * N_DIM;
    __shared__ unsigned hist[256];
    __shared__ int sel[2];
    __shared__ int cnts[2];
    __shared__ float vals[128];
    __shared__ int inds[128];
    __shared__ float scr[4];
    const int tid = threadIdx.x;
    unsigned prefix = 0;
    int kneed = 128;
    for (int pass = 0; pass < 4; ++pass) {
        const int sh = 24 - pass * 8;
        hist[tid] = 0;
        __syncthreads();
        for (int i = tid; i < N_DIM; i += 256) {
            unsigned u = __float_as_uint(row[i]);
            unsigned k = (u & 0x80000000u) ? ~u : (u | 0x80000000u);
            bool match = (pass == 0) || ((k >> (sh + 8)) == prefix);
            if (match) atomicAdd(&hist[(k >> sh) & 255u], 1u);
        }
        __syncthreads();
        if (tid == 0) {
            int acc = 0, d = 0;
            for (int dig = 255; dig >= 0; --dig) {
                int c = (int)hist[dig];
                if (acc + c >= kneed) { d = dig; break; }
                acc += c;
            }
            sel[0] = d; sel[1] = acc;
        }
        __syncthreads();
        kneed -= sel[1];
        prefix = (prefix << 8) | (unsigned)sel[0];
        __syncthreads();
    }
    const unsigned K = prefix;
    if (tid < 2) cnts[tid] = 0;
    if (tid < 128) { vals[tid] = -1.0e30f; inds[tid] = 0; }
    __syncthreads();
    for (int i = tid; i < N_DIM; i += 256) {
        float f = row[i];
        unsigned u = __float_as_uint(f);
        unsigned k = (u & 0x80000000u) ? ~u : (u | 0x80000000u);
        if (k > K) { int p = atomicAdd(&cnts[0], 1); if (p < 128) { vals[p] = f; inds[p] = i; } }
    }
    __syncthreads();
    const int cgt = min(cnts[0], 128);
    for (int i = tid; i < N_DIM; i += 256) {
        float f = row[i];
        unsigned u = __float_as_uint(f);
        unsigned k = (u & 0x80000000u) ? ~u : (u | 0x80000000u);
        if (k == K) {
            int p = atomicAdd(&cnts[1], 1);
            if (cgt + p < 128) { vals[cgt + p] = f; inds[cgt + p] = i; }
        }
    }
    __syncthreads();
    float xv = (tid < 128) ? vals[tid] : -3.0e38f;
    float mx = blk_max(xv, scr);
    float ex = (tid < 128) ? __expf(vals[tid] - mx) : 0.f;
    float sm = blk_sum(ex, scr);
    float lse = mx + __logf(fmaxf(sm, 1e-37f));
    if (tid < 128) {
        candg[t * 128 + tid] = min(max(inds[tid], 0), N_DIM - 1);
        lsmg[t * 128 + tid] = vals[tid] - lse;
    }
}

// -------- cast H to bf16 ----------------------------------------------------
__global__ void cast_h_k(const float* __restrict__ H, u16* __restrict__ Hbf) {
    size_t base = ((size_t)blockIdx.x * 256 + threadIdx.x) * 4;
    float4 f = *(const float4*)(H + base);
    ushort4 o;
    o.x = f2bf(f.x); o.y = f2bf(f.y); o.z = f2bf(f.z); o.w = f2bf(f.w);
    *(ushort4*)(Hbf + base) = o;
}

// -------- HW = H @ W (fp32 VALU, bf16 out); 8 rows per block ----------------
__global__ __launch_bounds__(256) void gemm_hw_k(const float* __restrict__ H,
                                                 const float* __restrict__ W,
                                                 u16* __restrict__ HWbf) {
    const int r0 = blockIdx.x * 8;
    __shared__ float Hl[8][512];
    for (int idx = threadIdx.x; idx < 8 * 512; idx += 256) {
        int r = idx >> 9, k = idx & 511;
        Hl[r][k] = H[(size_t)(r0 + r) * 512 + k];
    }
    __syncthreads();
    const int c = threadIdx.x;
    float acc0[8], acc1[8];
#pragma unroll
    for (int r = 0; r < 8; ++r) { acc0[r] = 0.f; acc1[r] = 0.f; }
    for (int k = 0; k < 512; ++k) {
        float w0 = W[(size_t)k * 512 + c];
        float w1 = W[(size_t)k * 512 + c + 256];
#pragma unroll
        for (int r = 0; r < 8; ++r) {
            float h = Hl[r][k];
            acc0[r] += h * w0;
            acc1[r] += h * w1;
        }
    }
#pragma unroll
    for (int r = 0; r < 8; ++r) {
        HWbf[(size_t)(r0 + r) * 512 + c] = f2bf(acc0[r]);
        HWbf[(size_t)(r0 + r) * 512 + c + 256] = f2bf(acc1[r]);
    }
}

// -------- per-step pair matrix -> (E row-major bf16, c fp32), pure VALU -----
__global__ __launch_bounds__(256) void pair_k(const int* __restrict__ candg,
                                              const float* __restrict__ lsmg,
                                              const u16* __restrict__ HWbf,
                                              const u16* __restrict__ Hbf,
                                              const void* __restrict__ allowed,
                                              const int* __restrict__ flag,
                                              u16* __restrict__ Eg,
                                              float* __restrict__ cvec) {
    const int t = blockIdx.x + 1;
    __shared__ u16 Hl[32][520];
    __shared__ int sprev[128], scur[128];
    __shared__ unsigned scm[32];
    __shared__ float scmf[32];
    const int tid = threadIdx.x;
    if (tid < 128) {
        sprev[tid] = min(max(candg[(t - 1) * 128 + tid], 0), N_DIM - 1);
        scur[tid]  = min(max(candg[t * 128 + tid], 0), N_DIM - 1);
    }
    __syncthreads();
    const int fl = *flag;
    const int i = tid >> 1;               // prev row 0..127
    const int jh = tid & 1;               // 16-column half of a 32-col pass
    const size_t prow = (size_t)sprev[i] * 512;
    u16* Eo = Eg + (size_t)(t - 1) * 16384;
    for (int p = 0; p < 4; ++p) {
        for (int idx = tid; idx < 32 * 64; idx += 256) {
            int r = idx >> 6, v = idx & 63;
            *(s8v*)&Hl[r][v * 8] = *(const s8v*)(Hbf + (size_t)scur[p * 32 + r] * 512 + v * 8);
        }
        if (tid < 32) scm[tid] = 0u;
        __syncthreads();
        float acc[16];
#pragma unroll
        for (int jj = 0; jj < 16; ++jj) acc[jj] = 0.f;
        for (int k8 = 0; k8 < 64; ++k8) {
            s8v hv = *(const s8v*)(HWbf + prow + k8 * 8);
            float a[8];
#pragma unroll
            for (int e = 0; e < 8; ++e) a[e] = b2f((u16)hv[e]);
#pragma unroll
            for (int jj = 0; jj < 16; ++jj) {
                s8v hl = *(const s8v*)&Hl[jh * 16 + jj][k8 * 8];
#pragma unroll
                for (int e = 0; e < 8; ++e) acc[jj] += a[e] * b2f((u16)hl[e]);
            }
        }
#pragma unroll
        for (int jj = 0; jj < 16; ++jj) {
            int jl = jh * 16 + jj;
            int j = p * 32 + jl;
            if (!mask_ok(allowed, fl, (size_t)scur[j] * N_DIM + (size_t)sprev[i])) acc[jj] += PEN;
            atomicMax(&scm[jl], fmapu(acc[jj]));
        }
        __syncthreads();
        if (tid < 32) {
            float cm = funmap(scm[tid]);
            scmf[tid] = cm;
            cvec[(size_t)(t - 1) * 128 + p * 32 + tid] = cm + lsmg[(size_t)t * 128 + p * 32 + tid];
        }
        __syncthreads();
#pragma unroll
        for (int jj = 0; jj < 16; ++jj) {
            int jl = jh * 16 + jj;
            float e = __expf(acc[jj] - scmf[jl]);      // arg <= 0 by construction
            e = fminf(fmaxf(e, 0.f), 1.0f);            // scrub any NaN/overshoot
            Eo[(size_t)i * 128 + p * 32 + jl] = f2bf(e);
        }
        __syncthreads();
    }
}

// -------- gold path scores --------------------------------------------------
__global__ __launch_bounds__(256) void score_k(const float* __restrict__ U,
                                               const int* __restrict__ gold,
                                               const void* __restrict__ allowed,
                                               const int* __restrict__ flag,
                                               const u16* __restrict__ HWbf,
                                               const u16* __restrict__ Hbf,
                                               float* __restrict__ accums) {
    const int t = blockIdx.x;
    __shared__ float scr[4];
    float part = 0.f;
    int gp = 0, gc = 0;
    if (t < L_DIM - 1) {
        gp = min(max(gold[t], 0), N_DIM - 1);
        gc = min(max(gold[t + 1], 0), N_DIM - 1);
        const u16* ar = HWbf + (size_t)gp * 512;
        const u16* br = Hbf + (size_t)gc * 512;
        for (int k = threadIdx.x; k < 512; k += 256)
            part += b2f(ar[k]) * b2f(br[k]);
    }
    float tot = blk_sum(part, scr);
    if (threadIdx.x == 0) {
        if (t < L_DIM - 1) {
            int ok = mask_ok(allowed, *flag, (size_t)gc * N_DIM + (size_t)gp);
            atomicAdd(&accums[1], ok ? tot : PEN);
        }
        int g0 = min(max(gold[t], 0), N_DIM - 1);
        atomicAdd(&accums[0], U[(size_t)t * N_DIM + g0]);
    }
}

// ===================== log-domain fp32 binary tree ==========================
// C[i][k] = max_j(A[i][j]+B[j][k]) + log(sum_j exp(A[i][j]+B[j][k]-max)).

// Level 1: inputs are pair_k's (E bf16 [i][k], c fp32 [k]); P[i][k]=log(E)+c[k]
__global__ __launch_bounds__(256) void l1comb_k(const u16* __restrict__ Eg,
                                                const float* __restrict__ cvec,
                                                float* __restrict__ Mout,
                                                int n_in) {
    const int o = blockIdx.x, rs = blockIdx.y;
    const int tid = threadIdx.x;
    const u16* E0 = Eg + (size_t)(2 * o) * 16384;
    const float* c0 = cvec + (size_t)(2 * o) * 128;
    float* C = Mout + (size_t)o * 16384;
    if (2 * o + 1 >= n_in) {   // pass-through convert
        for (int idx = tid; idx < 64 * 128; idx += 256) {
            int i = rs * 64 + (idx >> 7), k = idx & 127;
            C[(size_t)i * 128 + k] = loge(E0[(size_t)i * 128 + k]) + c0[k];
        }
        return;
    }
    __shared__ float At[128][64];     // A^T: At[j][i_local] = log E0[i][j] + c0[j]
    __shared__ float Bs[128 * 128];   // B:  Bs[j*128+k]    = log E1[j][k] + c1[k]
    __shared__ float sc0[128], sc1[128];
    const u16* E1 = Eg + (size_t)(2 * o + 1) * 16384;
    const float* c1 = cvec + (size_t)(2 * o + 1) * 128;
    if (tid < 128) { sc0[tid] = c0[tid]; sc1[tid] = c1[tid]; }
    __syncthreads();
    for (int idx = tid; idx < 64 * 128; idx += 256) {
        int il = idx & 63, j = idx >> 6;
        At[j][il] = loge(E0[(size_t)(rs * 64 + il) * 128 + j]) + sc0[j];
    }
    for (int idx = tid; idx < 16384; idx += 256)
        Bs[idx] = loge(E1[idx]) + sc1[idx & 127];
    __syncthreads();
    const int i0 = (tid & 15) * 4, k0 = (tid >> 4) * 8;
    float m[4][8], s[4][8];
#pragma unroll
    for (int a = 0; a < 4; ++a)
#pragma unroll
        for (int b = 0; b < 8; ++b) m[a][b] = -3.0e38f;
    for (int j = 0; j < 128; ++j) {
        float4 av = *(const float4*)&At[j][i0];
        float4 b0 = *(const float4*)&Bs[j * 128 + k0];
        float4 b1 = *(const float4*)&Bs[j * 128 + k0 + 4];
        float aa[4] = {av.x, av.y, av.z, av.w};
        float bb[8] = {b0.x, b0.y, b0.z, b0.w, b1.x, b1.y, b1.z, b1.w};
#pragma unroll
        for (int a = 0; a < 4; ++a)
#pragma unroll
            for (int b = 0; b < 8; ++b) m[a][b] = fmaxf(m[a][b], aa[a] + bb[b]);
    }
#pragma unroll
    for (int a = 0; a < 4; ++a)
#pragma unroll
        for (int b = 0; b < 8; ++b) s[a][b] = 0.f;
    for (int j = 0; j < 128; ++j) {
        float4 av = *(const float4*)&At[j][i0];
        float4 b0 = *(const float4*)&Bs[j * 128 + k0];
        float4 b1 = *(const float4*)&Bs[j * 128 + k0 + 4];
        float aa[4] = {av.x, av.y, av.z, av.w};
        float bb[8] = {b0.x, b0.y, b0.z, b0.w, b1.x, b1.y, b1.z, b1.w};
#pragma unroll
        for (int a = 0; a < 4; ++a)
#pragma unroll
            for (int b = 0; b < 8; ++b) s[a][b] += __expf(aa[a] + bb[b] - m[a][b]);
    }
#pragma unroll
    for (int a = 0; a < 4; ++a)
#pragma unroll
        for (int b = 0; b < 8; ++b)
            C[(size_t)(rs * 64 + i0 + a) * 128 + k0 + b] = m[a][b] + __logf(s[a][b]); // s>=1
}

// Levels 2+: fp32 log matrices in/out
__global__ __launch_bounds__(256) void comb_k(const float* __restrict__ Min,
                                              float* __restrict__ Mout, int n_in) {
    const int o = blockIdx.x, rs = blockIdx.y;
    const int tid = threadIdx.x;
    const float* A = Min + (size_t)(2 * o) * 16384;
    float* C = Mout + (size_t)o * 16384;
    if (2 * o + 1 >= n_in) {
        for (int idx = tid; idx < 64 * 128; idx += 256) {
            int i = rs * 64 + (idx >> 7), k = idx & 127;
            C[(size_t)i * 128 + k] = A[(size_t)i * 128 + k];
        }
        return;
    }
    __shared__ float At[128][64];
    __shared__ float Bs[128 * 128];
    const float* B = Min + (size_t)(2 * o + 1) * 16384;
    for (int idx = tid; idx < 64 * 128; idx += 256) {
        int il = idx & 63, j = idx >> 6;
        At[j][il] = A[(size_t)(rs * 64 + il) * 128 + j];
    }
    for (int idx = tid; idx < 16384; idx += 256) Bs[idx] = B[idx];
    __syncthreads();
    const int i0 = (tid & 15) * 4, k0 = (tid >> 4) * 8;
    float m[4][8], s[4][8];
#pragma unroll
    for (int a = 0; a < 4; ++a)
#pragma unroll
        for (int b = 0; b < 8; ++b) m[a][b] = -3.0e38f;
    for (int j = 0; j < 128; ++j) {
        float4 av = *(const float4*)&At[j][i0];
        float4 b0 = *(const float4*)&Bs[j * 128 + k0];
        float4 b1 = *(const float4*)&Bs[j * 128 + k0 + 4];
        float aa[4] = {av.x, av.y, av.z, av.w};
        float bb[8] = {b0.x, b0.y, b0.z, b0.w, b1.x, b1.y, b1.z, b1.w};
#pragma unroll
        for (int a = 0; a < 4; ++a)
#pragma unroll
            for (int b = 0; b < 8; ++b) m[a][b] = fmaxf(m[a][b], aa[a] + bb[b]);
    }
#pragma unroll
    for (int a = 0; a < 4; ++a)
#pragma unroll
        for (int b = 0; b < 8; ++b) s[a][b] = 0.f;
    for (int j = 0; j < 128; ++j) {
        float4 av = *(const float4*)&At[j][i0];
        float4 b0 = *(const float4*)&Bs[j * 128 + k0];
        float4 b1 = *(const float4*)&Bs[j * 128 + k0 + 4];
        float aa[4] = {av.x, av.y, av.z, av.w};
        float bb[8] = {b0.x, b0.y, b0.z, b0.w, b1.x, b1.y, b1.z, b1.w};
#pragma unroll
        for (int a = 0; a < 4; ++a)
#pragma unroll
            for (int b = 0; b < 8; ++b) s[a][b] += __expf(aa[a] + bb[b] - m[a][b]);
    }
#pragma unroll
    for (int a = 0; a < 4; ++a)
#pragma unroll
        for (int b = 0; b < 8; ++b)
            C[(size_t)(rs * 64 + i0 + a) * 128 + k0 + b] = m[a][b] + __logf(s[a][b]);
}

// -------- final: alpha0 through 32 log-matrices, online LSE, ILP-batched ----
// One pass per step: running (m,s) per output k; i-range split over the two
// thread-halves (256 threads active), merged via LDS. s>=1 in the max half,
// so merged ss>=1: no log guard needed. unroll 8 => 8 loads in flight.
__global__ __launch_bounds__(256) void tfinal_k(const float* __restrict__ M5,
                                                const float* __restrict__ lsmg,
                                                const float* __restrict__ accums,
                                                float* __restrict__ out) {
    __shared__ float v[128];
    __shared__ float pm[2][128], ps[2][128];
    __shared__ float scr[4];
    const int tid = threadIdx.x;
    const int k = tid & 127, h = tid >> 7;
    if (tid < 128) v[tid] = lsmg[tid];   // alpha0
    __syncthreads();
    for (int s = 0; s < 32; ++s) {
        const float* M = M5 + (size_t)s * 16384 + (size_t)h * 64 * 128 + k;
        const float* vh = &v[h * 64];
        float m = -3.0e38f, sum = 0.f;
#pragma unroll 8
        for (int i = 0; i < 64; ++i) {
            float a = vh[i] + M[(size_t)i * 128];
            float nm = fmaxf(m, a);
            sum = sum * __expf(m - nm) + __expf(a - nm);
            m = nm;
        }
        pm[h][k] = m; ps[h][k] = sum;
        __syncthreads();
        if (tid < 128) {
            float m0 = pm[0][tid], m1 = pm[1][tid];
            float mm = fmaxf(m0, m1);
            float ss = ps[0][tid] * __expf(m0 - mm) + ps[1][tid] * __expf(m1 - mm);
            v[tid] = mm + __logf(ss);   // ss >= 1
        }
        __syncthreads();
    }
    float x = (tid < 128) ? v[tid] : -3.0e38f;
    float mz = blk_max(x, scr);
    float e = (tid < 128) ? __expf(v[tid] - mz) : 0.f;
    float sm = blk_sum(e, scr);
    if (tid == 0) out[0] = mz + __logf(fmaxf(sm, 1e-37f)) - (accums[0] + accums[1]);
}

extern "C" void kernel_launch(void* const* d_in, const int* in_sizes, int n_in,
                              void* d_out, int out_size, void* d_ws, size_t ws_size,
                              hipStream_t stream) {
    const float* U = (const float*)d_in[0];
    const float* H = (const float*)d_in[1];
    const float* W = (const float*)d_in[2];
    const int* gold = (const int*)d_in[3];
    const void* allowed = (const void*)d_in[4];

    char* ws = (char*)d_ws;
    float* accums = (float*)ws;            // [0]=score_unary, [1]=score_pair
    int* flag = (int*)(ws + 8);
    size_t off = 256;
    int* cand = (int*)(ws + off);     off += (size_t)L_DIM * R_DIM * 4;
    float* lsm = (float*)(ws + off);  off += (size_t)L_DIM * R_DIM * 4;
    u16* Hbf = (u16*)(ws + off);      off += (size_t)N_DIM * 512 * 2;      // 16 MB
    u16* HWbf = (u16*)(ws + off);     off += (size_t)N_DIM * 512 * 2;      // 16 MB
    u16* E = (u16*)(ws + off);        off += (size_t)(L_DIM - 1) * 16384 * 2; // 32 MB
    float* cvec = (float*)(ws + off); off += (size_t)(L_DIM - 1) * 128 * 4;

    // Tree buffers OVERLAY dead regions:
    // MA (32 MB) = Hbf+HWbf region — dead after score_k, written by L1.
    // MB (16 MB) = E region       — dead after L1 reads it, written by L2.
    float* MA = (float*)Hbf;
    float* MB = (float*)E;

    hipMemsetAsync(d_ws, 0, 256, stream);
    detect_k<<<1, 256, 0, stream>>>((const unsigned*)d_in[4], flag);
    topk_lsm_k<<<L_DIM, 256, 0, stream>>>(U, cand, lsm);
    cast_h_k<<<(N_DIM * 512) / (256 * 4), 256, 0, stream>>>(H, Hbf);
    gemm_hw_k<<<N_DIM / 8, 256, 0, stream>>>(H, W, HWbf);
    pair_k<<<L_DIM - 1, 256, 0, stream>>>(cand, lsm, HWbf, Hbf, allowed, flag, E, cvec);
    score_k<<<L_DIM, 256, 0, stream>>>(U, gold, allowed, flag, HWbf, Hbf, accums);
    // binary tree: 1023 -> 512 -> 256 -> 128 -> 64 -> 32, then 32-step scan
    l1comb_k<<<dim3(512, 2), 256, 0, stream>>>(E, cvec, MA, 1023);
    comb_k<<<dim3(256, 2), 256, 0, stream>>>(MA, MB, 512);
    comb_k<<<dim3(128, 2), 256, 0, stream>>>(MB, MA, 256);
    comb_k<<<dim3(64, 2), 256, 0, stream>>>(MA, MB, 128);
    comb_k<<<dim3(32, 2), 256, 0, stream>>>(MB, MA, 64);
    tfinal_k<<<1, 256, 0, stream>>>(MA, lsm, accums, (float*)d_out);
}